// Round 9
// baseline (426.552 us; speedup 1.0000x reference)
//
#include <hip/hip_runtime.h>
#include <hip/hip_bf16.h>
#include <math.h>

#define M_TOT 4096
#define K_TOT 1024
#define V_TOT 32000

typedef short short8 __attribute__((ext_vector_type(8)));
typedef float f32x4 __attribute__((ext_vector_type(4)));

__device__ __forceinline__ void gload_lds16(const void* g, void* l) {
  __builtin_amdgcn_global_load_lds(
      (const __attribute__((address_space(1))) void*)g,
      (__attribute__((address_space(3))) void*)l, 16, 0, 0);
}

__device__ __forceinline__ unsigned short f2bf(float f) {
  unsigned int u = __builtin_bit_cast(unsigned int, f);
  unsigned int lsb = (u >> 16) & 1u;
  u += 0x7fffu + lsb;
  return (unsigned short)(u >> 16);
}

__device__ __forceinline__ float sani(float v) {
  return (v != v) ? 0.0f : fminf(fmaxf(v, -1e4f), 1e4f);
}

__global__ void prep_h(const float* __restrict__ h, unsigned short* __restrict__ hbf,
                       float* __restrict__ h0) {
  int m = blockIdx.x;
  int t = threadIdx.x;
  const float* row = h + (long)m * (K_TOT + 1);
  if (t == 0) h0[m] = sani(row[0]);
  unsigned short* dst = hbf + (long)m * K_TOT;
#pragma unroll
  for (int j = 0; j < 4; ++j) {
    int idx = t * 4 + j;
    dst[idx] = f2bf(sani(row[1 + idx]));
  }
}

__global__ void prep_w(const float* __restrict__ w, unsigned short* __restrict__ wbf,
                       float* __restrict__ wtime) {
  __shared__ float red[4];
  __shared__ float r_sh;
  int v = blockIdx.x;
  int t = threadIdx.x;
  const float* row = w + (long)v * K_TOT;
  float4 x = *(const float4*)(row + t * 4);
  float s = x.x * x.x + x.y * x.y + x.z * x.z + x.w * x.w;
#pragma unroll
  for (int off = 32; off > 0; off >>= 1) s += __shfl_down(s, off);
  int lane = t & 63, wv = t >> 6;
  if (lane == 0) red[wv] = s;
  __syncthreads();
  if (t == 0) {
    float tot = red[0] + red[1] + red[2] + red[3];
    float norm = sqrtf(tot);
    float r = (norm > 1e-7f) ? (sinhf(norm) / fmaxf(norm, 1e-7f)) : 1.0f;
    r_sh = r;
    wtime[v] = coshf(norm);
  }
  __syncthreads();
  float r = r_sh;
  ushort4 pack;
  pack.x = f2bf(r * x.x);
  pack.y = f2bf(r * x.y);
  pack.z = f2bf(r * x.z);
  pack.w = f2bf(r * x.w);
  *(ushort4*)(wbf + (long)v * K_TOT + t * 4) = pack;
}

// ---- 256x128 tile, 4 waves, 2 blocks/CU desynchronized GEMM ---------------
// Rationale (r8 post-mortem): with one 8-wave block/CU, MFMA (33k cyc), LDS
// (~45k) and HBM/store (~43k+26k) run nearly serially because every barrier/
// vmcnt/epilogue stalls the whole CU. Here each SIMD hosts 1 wave from EACH
// of 2 independent blocks: when block A waits (vmcnt, barrier, store drain),
// block B's wave keeps issuing MFMA -> pipe overlap without intra-block
// scheduling heroics.
// Carried-over proven pieces: zero-conflict XOR swizzle (r4-r8: slot chunk c
// holds global chunk c ^ ((row>>1)&3); source pre-swizzled cc=(t&3)^((t>>3)&3);
// read chunk = fq ^ ((fr>>1)&3); both sides same involution, rule #21).
// Operand-swapped MFMA (v on acc reg axis -> float4 stores; WRITE=513MB=ideal,
// r7/r8). XCD-bijective grid grouping (16 consecutive blocks share a B-panel).
// Counted vmcnt (never 0 in-loop), triple buffer, 2-K-tile staging lead,
// ONE barrier per K-tile (stage targets buf (kt+2)%3, readers on kt%3; the
// overwritten buffer's readers all passed the previous barrier).
// Registers: acc[8][4]=128 AGPR + ~92 VGPR = ~220 combined; launch_bounds
// (256,2) caps at 256 -> no spill (r4 lesson: don't cap below acc size).
// LDS: 3 bufs x 24KB = 72KB; 2 blocks = 144KB <= 160KB -> 2 blocks/CU.
#define BAR __builtin_amdgcn_s_barrier()
#define VM6 asm volatile("s_waitcnt vmcnt(6)" ::: "memory")
#define RD8(off) (*(const short8*)(smem + (off)))

__global__ __launch_bounds__(256, 2) void gemm_geo(
    const unsigned short* __restrict__ hbf, const unsigned short* __restrict__ wbf,
    const float* __restrict__ h0, const float* __restrict__ wtime,
    const float* __restrict__ ls, float* __restrict__ out) {
  __shared__ __align__(16) char smem[73728];  // 3 x (A 16KB + B 8KB)

  const int t = threadIdx.x;
  const int wave = t >> 6, lane = t & 63;
  const int fr = lane & 15, fq = lane >> 4;
  const int wm = wave >> 1, wn = wave & 1;  // 2 (M) x 2 (N) wave grid

  // XCD-bijective swizzle: 4000 blocks, 500/XCD; 16 consecutive blocks per
  // XCD share one 256KB B-panel (concurrent L2 reuse).
  const int bid = blockIdx.x;
  const int swz = (bid & 7) * 500 + (bid >> 3);
  const int tile_v = swz >> 4;   // [0,250)
  const int tile_m = swz & 15;   // [0,16)
  const int row0 = tile_m * 256;
  const int col0 = tile_v * 128;

  // ds_read lane bases (bytes), + buf*24576 + frag*1024
  const int sw = (fq ^ ((fr >> 1) & 3)) * 16;
  const int a_rd = (wm * 128 + fr) * 64 + sw;
  const int b_rd = 16384 + (wn * 64 + fr) * 64 + sw;

  // staging: thread t -> row h*64 + (t>>2), slot chunk t&3; source k-chunk
  // pre-swizzled (h*64 doesn't touch row bits 1-2, so formula is t-only)
  const int cc = (t & 3) ^ ((t >> 3) & 3);
  const unsigned short* pA = hbf + ((long)row0 + (t >> 2)) * K_TOT + cc * 8;
  const unsigned short* pB = wbf + ((long)col0 + (t >> 2)) * K_TOT + cc * 8;
  const int dst_w = wave * 1024;  // wave-uniform; HW adds lane*16

  auto STAGE = [&](int kt, int sb) {
#pragma unroll
    for (int h = 0; h < 4; ++h)  // A: 256 rows = 4 x 64-row batches
      gload_lds16(pA + (long)h * 65536 + kt * 32,
                  smem + sb * 24576 + h * 4096 + dst_w);
#pragma unroll
    for (int h = 0; h < 2; ++h)  // B: 128 rows = 2 batches
      gload_lds16(pB + (long)h * 65536 + kt * 32,
                  smem + sb * 24576 + 16384 + h * 4096 + dst_w);
  };

  f32x4 acc[8][4];
#pragma unroll
  for (int i = 0; i < 8; ++i)
#pragma unroll
    for (int j = 0; j < 4; ++j) acc[i][j] = (f32x4)(0.0f);

  // prologue: tiles 0,1 -> bufs 0,1 (12 loads); vmcnt(6): tile0's 6 landed.
  STAGE(0, 0);
  STAGE(1, 1);
  VM6;
  BAR;

#pragma unroll 1
  for (int kt = 0; kt < 32; ++kt) {
    const int cb = kt % 3;
    const int sg = (kt + 2 < 32) ? kt + 2 : 31;  // clamped redundant tail
    const int sb = (kt + 2) % 3;

    STAGE(sg, sb);  // 6 loads for tile kt+2 (issue early, 2-tile lead)

    const int abase = a_rd + cb * 24576;
    const int bbase = b_rd + cb * 24576;
    short8 af[8], bf[4];
#pragma unroll
    for (int iv = 0; iv < 4; ++iv) bf[iv] = RD8(bbase + iv * 1024);
#pragma unroll
    for (int im = 0; im < 8; ++im) af[im] = RD8(abase + im * 1024);

    __builtin_amdgcn_s_setprio(1);
#pragma unroll
    for (int im = 0; im < 8; ++im)
#pragma unroll
      for (int iv = 0; iv < 4; ++iv)
        acc[im][iv] = __builtin_amdgcn_mfma_f32_16x16x32_bf16(
            bf[iv], af[im], acc[im][iv], 0, 0, 0);
    __builtin_amdgcn_s_setprio(0);

    // boundary: tile kt+1's 6 loads (7-12 back) proven landed; kt+2's 6 fly.
    VM6;
    BAR;
  }

  // fused epilogue: x = h0*w_time - dot; d2 = safe_acosh(x)^2; out = -tau*d2
  // (operand swap put v on the acc reg axis -> float4 stores, m on lanes)
  const float ntau = -fminf(fmaxf(ls[0], 0.01f), 2.5f);
  const float LN2 = 0.69314718055994531f;
  f32x4 wt4[4];
#pragma unroll
  for (int iv = 0; iv < 4; ++iv)
    wt4[iv] = *(const f32x4*)&wtime[col0 + wn * 64 + iv * 16 + fq * 4];
#pragma unroll
  for (int im = 0; im < 8; ++im) {
    const float hh = h0[row0 + wm * 128 + im * 16 + fr];
    float* orow =
        out + (long)(row0 + wm * 128 + im * 16 + fr) * V_TOT + col0 + wn * 64;
#pragma unroll
    for (int iv = 0; iv < 4; ++iv) {
      f32x4 r;
#pragma unroll
      for (int j = 0; j < 4; ++j) {
        float x = fmaf(hh, wt4[iv][j], -acc[im][iv][j]);
        float xm1 = fmaxf(x - 1.0f, 0.0f);
        float arg = fmaxf(fmaf(x, x, -1.0f), 0.0f);
        float lg2 = __builtin_amdgcn_logf(x + __builtin_amdgcn_sqrtf(arg));
        float dex = LN2 * lg2;
        float d2_exact = dex * dex;
        float ts = fmaf(xm1, -1.0f / 12.0f, 1.0f);
        float d2_tay = 2.0f * xm1 * ts * ts;
        float d2 = (xm1 < 1e-3f) ? d2_tay : d2_exact;
        r[j] = ntau * d2;
      }
      *(f32x4*)(orow + iv * 16 + fq * 4) = r;
    }
  }
}

extern "C" void kernel_launch(void* const* d_in, const int* in_sizes, int n_in,
                              void* d_out, int out_size, void* d_ws, size_t ws_size,
                              hipStream_t stream) {
  const float* h = (const float*)d_in[0];   // [2,2048,1025]
  const float* w = (const float*)d_in[1];   // [32000,1024]
  const float* ls = (const float*)d_in[2];  // scalar
  float* out = (float*)d_out;               // [2,2048,32000] fp32

  char* ws = (char*)d_ws;
  unsigned short* wbf = (unsigned short*)ws;                  // 65,536,000 B
  unsigned short* hbf = (unsigned short*)(ws + 65536000);     // 8,388,608 B
  float* wtime = (float*)(ws + 65536000 + 8388608);           // 128,000 B
  float* h0 = (float*)(ws + 65536000 + 8388608 + 128000);     // 16,384 B

  prep_h<<<M_TOT, 256, 0, stream>>>(h, hbf, h0);
  prep_w<<<V_TOT, 256, 0, stream>>>(w, wbf, wtime);
  gemm_geo<<<4000, 256, 0, stream>>>(hbf, wbf, h0, wtime, ls, out);
}

// Round 10
// 390.616 us; speedup vs baseline: 1.0920x; 1.0920x over previous
//
#include <hip/hip_runtime.h>
#include <hip/hip_bf16.h>
#include <math.h>

#define M_TOT 4096
#define K_TOT 1024
#define V_TOT 32000

typedef short short8 __attribute__((ext_vector_type(8)));
typedef float f32x4 __attribute__((ext_vector_type(4)));

__device__ __forceinline__ void gload_lds16(const void* g, void* l) {
  __builtin_amdgcn_global_load_lds(
      (const __attribute__((address_space(1))) void*)g,
      (__attribute__((address_space(3))) void*)l, 16, 0, 0);
}

__device__ __forceinline__ unsigned short f2bf(float f) {
  unsigned int u = __builtin_bit_cast(unsigned int, f);
  unsigned int lsb = (u >> 16) & 1u;
  u += 0x7fffu + lsb;
  return (unsigned short)(u >> 16);
}

__device__ __forceinline__ float sani(float v) {
  return (v != v) ? 0.0f : fminf(fmaxf(v, -1e4f), 1e4f);
}

__global__ void prep_h(const float* __restrict__ h, unsigned short* __restrict__ hbf,
                       float* __restrict__ h0) {
  int m = blockIdx.x;
  int t = threadIdx.x;
  const float* row = h + (long)m * (K_TOT + 1);
  if (t == 0) h0[m] = sani(row[0]);
  unsigned short* dst = hbf + (long)m * K_TOT;
#pragma unroll
  for (int j = 0; j < 4; ++j) {
    int idx = t * 4 + j;
    dst[idx] = f2bf(sani(row[1 + idx]));
  }
}

__global__ void prep_w(const float* __restrict__ w, unsigned short* __restrict__ wbf,
                       float* __restrict__ wtime) {
  __shared__ float red[4];
  __shared__ float r_sh;
  int v = blockIdx.x;
  int t = threadIdx.x;
  const float* row = w + (long)v * K_TOT;
  float4 x = *(const float4*)(row + t * 4);
  float s = x.x * x.x + x.y * x.y + x.z * x.z + x.w * x.w;
#pragma unroll
  for (int off = 32; off > 0; off >>= 1) s += __shfl_down(s, off);
  int lane = t & 63, wv = t >> 6;
  if (lane == 0) red[wv] = s;
  __syncthreads();
  if (t == 0) {
    float tot = red[0] + red[1] + red[2] + red[3];
    float norm = sqrtf(tot);
    float r = (norm > 1e-7f) ? (sinhf(norm) / fmaxf(norm, 1e-7f)) : 1.0f;
    r_sh = r;
    wtime[v] = coshf(norm);
  }
  __syncthreads();
  float r = r_sh;
  ushort4 pack;
  pack.x = f2bf(r * x.x);
  pack.y = f2bf(r * x.y);
  pack.z = f2bf(r * x.z);
  pack.w = f2bf(r * x.w);
  *(ushort4*)(wbf + (long)v * K_TOT + t * 4) = pack;
}

// ====== 256x256, BK=64, 8-wave, 4-phase counted pipeline (m201 regime) =====
// LDS (128 KB): buf*65536 + {A: ri*128 + c*16 (ri 0..255, c 0..7)}
//                         + {B: 32768 + ks*16384 + rb*64 + c*16 (c 0..3)}
// A halves INTERLEAVED by wm: half0 = global rows {0-63,128-191} (the m0-3
// rows of BOTH wm), half1 = {64-127,192-255}. B halves split by k (ks half).
// => each staged half is first READ 2-3 phases after issue (progressive
// consumption; no monolithic tile wait).
// Swizzles (both-sides involutions, rule #21; r4-r9 measured 0 conflicts for
// this construction): A rows are 128 B (full bank period) -> slot c holds
// global chunk c^(ri&7); B rows 64 B (half period) -> c^((rb>>1)&3). Sources
// pre-swizzled since gload_lds writes linearly.
// Per K-tile kt (compute buf cb=kt&1, stage tile kt+1 -> nb):
//  P1: stage A0'; vmcnt(4) [proves A1(kt)]; BAR; read af4-7ks0; MFMA ks0 m0-3
//  P2: stage B0'; vmcnt(4) [proves B1(kt)]; BAR; read bf1+af0-3ks1; MFMA ks0 m4-7
//  P3: stage A1';            BAR; read af4-7ks1;                  MFMA ks1 m0-3
//  P4: stage B1'; vmcnt(4) [proves A0',B0']; BAR; read af0-3ks0'+bf0' (buf nb!);
//      MFMA ks1 m4-7
// Ledger (2 loads/half, in-order retire): every wait is vmcnt(4), every half
// has >=2 phases of flight, pipeline NEVER drains. ds_reads are one phase
// ahead of their MFMA (ping-pong regs) -> LDS latency hides under MFMA; the
// compiler emits counted lgkmcnt for the in-flight reads.
// Buffer-overwrite safety: each LDS region's restage is >=2 barriers after
// its last read issue (A0: read P4/P2, restaged P1+4phases; A1: read P1/P3,
// restaged P3'; B0: read P4/P1/P2... all checked).
// launch_bounds(512,2): VGPR cap 256; acc 128 + frags 64 + misc ~40 fits.
// (512,4) would cap at 64 -> acc spill -> r4's 13.9GB disaster. 1 block/CU.
#define BAR __builtin_amdgcn_s_barrier()
#define FENCE asm volatile("" ::: "memory")
#define VM4 asm volatile("s_waitcnt vmcnt(4)" ::: "memory")
#define RD8(off) (*(const short8*)(smem + (off)))

__global__ __launch_bounds__(512, 2) void gemm_geo(
    const unsigned short* __restrict__ hbf, const unsigned short* __restrict__ wbf,
    const float* __restrict__ h0, const float* __restrict__ wtime,
    const float* __restrict__ ls, float* __restrict__ out) {
  __shared__ __align__(16) char smem[131072];

  const int t = threadIdx.x;
  const int wave = t >> 6, lane = t & 63;
  const int fr = lane & 15, fq = lane >> 4;
  const int wm = wave >> 2, wn = wave & 3;  // 2 (M) x 4 (N) wave grid

  // XCD-bijective grid: 2000 blocks (125 v-tiles x 16 m-tiles), 250/XCD;
  // 16 consecutive share one 512KB B-panel (measured FETCH ~309MB, r5).
  const int bid = blockIdx.x;
  const int swz = (bid & 7) * 250 + (bid >> 3);
  const int tile_v = swz >> 4;   // [0,125)
  const int tile_m = swz & 15;   // [0,16)
  const int row0 = tile_m * 256;
  const int col0 = tile_v * 256;

  // read-side lane constants (bytes)
  const int a_rd = (wm * 64 + fr) * 128;           // + s*2048 (+16384 if s>=4)
  const int asz0 = (fq ^ (fr & 7)) * 16;           // ks0 chunk
  const int asz1 = ((4 + fq) ^ (fr & 7)) * 16;     // ks1 chunk
  const int b_rd = 32768 + (wn * 64 + fr) * 64 + (fq ^ ((fr >> 1) & 3)) * 16;
  // bf(n,ks,buf): buf + b_rd + ks*16384 + n*1024

  // staging source pointers (pre-swizzled chunks)
  const unsigned short* pA_th =
      hbf + ((long)row0 + (t >> 3)) * K_TOT + ((t & 7) ^ ((t >> 3) & 7)) * 8;
  const unsigned short* pB_th =
      wbf + ((long)col0 + (t >> 2)) * K_TOT + ((t & 3) ^ ((t >> 3) & 3)) * 8;

  auto STAGE_A = [&](int h, int ktile, int bufo) {
#pragma unroll
    for (int l = 0; l < 2; ++l)
      gload_lds16(pA_th + (long)(h * 64 + l * 128) * K_TOT + ktile * 64,
                  smem + bufo + h * 16384 + (l * 512 + wave * 64) * 16);
  };
  auto STAGE_B = [&](int ks, int ktile, int bufo) {
#pragma unroll
    for (int l = 0; l < 2; ++l)
      gload_lds16(pB_th + (long)l * 128 * K_TOT + ktile * 64 + ks * 32,
                  smem + bufo + 32768 + ks * 16384 + (l * 512 + wave * 64) * 16);
  };

  f32x4 acc[8][4];
#pragma unroll
  for (int i = 0; i < 8; ++i)
#pragma unroll
    for (int j = 0; j < 4; ++j) acc[i][j] = (f32x4)(0.0f);

  short8 afX[4], afY[4], bfA[4], bfB[4];

  // prologue: tile0's 4 halves in steady-state order; vmcnt(4) proves A0,B0;
  // pre-read P1's frags (af0-3ks0 -> afX, bf0 -> bfA).
  STAGE_A(0, 0, 0); STAGE_B(0, 0, 0); STAGE_A(1, 0, 0); STAGE_B(1, 0, 0);
  VM4; FENCE; BAR; FENCE;
#pragma unroll
  for (int i = 0; i < 4; ++i) afX[i] = RD8(a_rd + i * 2048 + asz0);
#pragma unroll
  for (int n = 0; n < 4; ++n) bfA[n] = RD8(b_rd + n * 1024);

#define MF16(mb, AF, BF)                                                     \
  {                                                                          \
    __builtin_amdgcn_s_setprio(1);                                           \
    _Pragma("unroll") for (int i = 0; i < 4; ++i)                            \
        _Pragma("unroll") for (int n = 0; n < 4; ++n) acc[(mb) + i][n] =     \
            __builtin_amdgcn_mfma_f32_16x16x32_bf16(BF[n], AF[i],            \
                                                    acc[(mb) + i][n], 0, 0, 0); \
    __builtin_amdgcn_s_setprio(0);                                           \
  }

#pragma unroll 1
  for (int kt = 0; kt < 16; ++kt) {
    const int cbo = (kt & 1) * 65536;
    const int nbo = cbo ^ 65536;
    const int nkt = (kt + 1 < 16) ? kt + 1 : 15;  // clamped redundant tail

    // P1: MFMA(ks0, m0-3); read af4-7ks0; stage A0(kt+1)
    STAGE_A(0, nkt, nbo);
    VM4; FENCE; BAR; FENCE;
#pragma unroll
    for (int i = 0; i < 4; ++i) afY[i] = RD8(cbo + a_rd + 16384 + i * 2048 + asz0);
    MF16(0, afX, bfA);

    // P2: MFMA(ks0, m4-7); read bf1 + af0-3ks1; stage B0(kt+1)
    STAGE_B(0, nkt, nbo);
    VM4; FENCE; BAR; FENCE;
#pragma unroll
    for (int n = 0; n < 4; ++n) bfB[n] = RD8(cbo + b_rd + 16384 + n * 1024);
#pragma unroll
    for (int i = 0; i < 4; ++i) afX[i] = RD8(cbo + a_rd + i * 2048 + asz1);
    MF16(4, afY, bfA);

    // P3: MFMA(ks1, m0-3); read af4-7ks1; stage A1(kt+1)  [no vmcnt]
    STAGE_A(1, nkt, nbo);
    FENCE; BAR; FENCE;
#pragma unroll
    for (int i = 0; i < 4; ++i) afY[i] = RD8(cbo + a_rd + 16384 + i * 2048 + asz1);
    MF16(0, afX, bfB);

    // P4: MFMA(ks1, m4-7); read af0-3ks0 + bf0 from NEXT buf; stage B1(kt+1)
    STAGE_B(1, nkt, nbo);
    VM4; FENCE; BAR; FENCE;
#pragma unroll
    for (int i = 0; i < 4; ++i) afX[i] = RD8(nbo + a_rd + i * 2048 + asz0);
#pragma unroll
    for (int n = 0; n < 4; ++n) bfA[n] = RD8(nbo + b_rd + n * 1024);
    MF16(4, afY, bfB);
  }

  // fused epilogue (r7/r8-proven): x = h0*w_time - dot; d2 = acosh(x)^2;
  // out = -tau*d2. Operand-swapped MFMA put v on the acc-reg axis -> float4
  // stores (WRITE_SIZE measured 513MB = ideal).
  const float ntau = -fminf(fmaxf(ls[0], 0.01f), 2.5f);
  const float LN2 = 0.69314718055994531f;
  f32x4 wt4[4];
#pragma unroll
  for (int iv = 0; iv < 4; ++iv)
    wt4[iv] = *(const f32x4*)&wtime[col0 + wn * 64 + iv * 16 + fq * 4];
#pragma unroll
  for (int im = 0; im < 8; ++im) {
    const float hh = h0[row0 + wm * 128 + im * 16 + fr];
    float* orow =
        out + (long)(row0 + wm * 128 + im * 16 + fr) * V_TOT + col0 + wn * 64;
#pragma unroll
    for (int iv = 0; iv < 4; ++iv) {
      f32x4 r;
#pragma unroll
      for (int j = 0; j < 4; ++j) {
        float x = fmaf(hh, wt4[iv][j], -acc[im][iv][j]);
        float xm1 = fmaxf(x - 1.0f, 0.0f);
        float arg = fmaxf(fmaf(x, x, -1.0f), 0.0f);
        float lg2 = __builtin_amdgcn_logf(x + __builtin_amdgcn_sqrtf(arg));
        float dex = LN2 * lg2;
        float d2_exact = dex * dex;
        float ts = fmaf(xm1, -1.0f / 12.0f, 1.0f);
        float d2_tay = 2.0f * xm1 * ts * ts;
        float d2 = (xm1 < 1e-3f) ? d2_tay : d2_exact;
        r[j] = ntau * d2;
      }
      *(f32x4*)(orow + iv * 16 + fq * 4) = r;
    }
  }
}

extern "C" void kernel_launch(void* const* d_in, const int* in_sizes, int n_in,
                              void* d_out, int out_size, void* d_ws, size_t ws_size,
                              hipStream_t stream) {
  const float* h = (const float*)d_in[0];   // [2,2048,1025]
  const float* w = (const float*)d_in[1];   // [32000,1024]
  const float* ls = (const float*)d_in[2];  // scalar
  float* out = (float*)d_out;               // [2,2048,32000] fp32

  char* ws = (char*)d_ws;
  unsigned short* wbf = (unsigned short*)ws;                  // 65,536,000 B
  unsigned short* hbf = (unsigned short*)(ws + 65536000);     // 8,388,608 B
  float* wtime = (float*)(ws + 65536000 + 8388608);           // 128,000 B
  float* h0 = (float*)(ws + 65536000 + 8388608 + 128000);     // 16,384 B

  prep_h<<<M_TOT, 256, 0, stream>>>(h, hbf, h0);
  prep_w<<<V_TOT, 256, 0, stream>>>(w, wbf, wtime);
  gemm_geo<<<2000, 512, 0, stream>>>(hbf, wbf, h0, wtime, ls, out);
}

// Round 11
// 289.896 us; speedup vs baseline: 1.4714x; 1.3474x over previous
//
#include <hip/hip_runtime.h>
#include <hip/hip_bf16.h>
#include <hip/hip_fp8.h>
#include <math.h>

#define M_TOT 4096
#define K_TOT 1024
#define V_TOT 32000

typedef int int4v __attribute__((ext_vector_type(4)));
typedef int int8v __attribute__((ext_vector_type(8)));
typedef float f32x4 __attribute__((ext_vector_type(4)));

__device__ __forceinline__ void gload_lds16(const void* g, void* l) {
  __builtin_amdgcn_global_load_lds(
      (const __attribute__((address_space(1))) void*)g,
      (__attribute__((address_space(3))) void*)l, 16, 0, 0);
}

__device__ __forceinline__ float sani(float v) {
  return (v != v) ? 0.0f : fminf(fmaxf(v, -1e4f), 1e4f);
}

// pack 4 floats -> 4 fp8 e4m3 bytes (RNE, saturating)
__device__ __forceinline__ int pk4_fp8(float a, float b, float c, float d) {
#if __has_builtin(__builtin_amdgcn_cvt_pk_fp8_f32)
  int p = __builtin_amdgcn_cvt_pk_fp8_f32(a, b, 0, false);
  p = __builtin_amdgcn_cvt_pk_fp8_f32(c, d, p, true);
  return p;
#else
  union { unsigned char b4[4]; int i; } u;
  u.b4[0] = __hip_fp8_e4m3(a).__x;
  u.b4[1] = __hip_fp8_e4m3(b).__x;
  u.b4[2] = __hip_fp8_e4m3(c).__x;
  u.b4[3] = __hip_fp8_e4m3(d).__x;
  return u.i;
#endif
}

// hidden_states [4096][1025] f32 -> h0 f32 [4096], h8 fp8 [4096][1024]
__global__ void prep_h(const float* __restrict__ h, unsigned char* __restrict__ h8,
                       float* __restrict__ h0) {
  int m = blockIdx.x;
  int t = threadIdx.x;
  const float* row = h + (long)m * (K_TOT + 1);
  if (t == 0) h0[m] = sani(row[0]);
  float4 x = *(const float4*)(row + 1 + t * 4);
  ((int*)(h8 + (long)m * K_TOT))[t] =
      pk4_fp8(sani(x.x), sani(x.y), sani(x.z), sani(x.w));
}

// weight [32000][1024] f32 -> wtime f32 [V], w8 = fp8(16 * r * w) [V][1024]
// (the 16x prescale keeps w out of e4m3 denormal range; folded back via the
//  MFMA's uniform e8m0 scale byte 0x7B = 2^-4)
__global__ void prep_w(const float* __restrict__ w, unsigned char* __restrict__ w8,
                       float* __restrict__ wtime) {
  __shared__ float red[4];
  __shared__ float r_sh;
  int v = blockIdx.x;
  int t = threadIdx.x;
  const float* row = w + (long)v * K_TOT;
  float4 x = *(const float4*)(row + t * 4);
  float s = x.x * x.x + x.y * x.y + x.z * x.z + x.w * x.w;
#pragma unroll
  for (int off = 32; off > 0; off >>= 1) s += __shfl_down(s, off);
  int lane = t & 63, wv = t >> 6;
  if (lane == 0) red[wv] = s;
  __syncthreads();
  if (t == 0) {
    float tot = red[0] + red[1] + red[2] + red[3];
    float norm = sqrtf(tot);
    float r = (norm > 1e-7f) ? (sinhf(norm) / fmaxf(norm, 1e-7f)) : 1.0f;
    r_sh = r;
    wtime[v] = coshf(norm);
  }
  __syncthreads();
  float sc = 16.0f * r_sh;
  ((int*)(w8 + (long)v * K_TOT))[t] =
      pk4_fp8(sc * x.x, sc * x.y, sc * x.z, sc * x.w);
}

// ====== 256x256 tile, BK=128, MX-fp8 (e4m3) double-buffered GEMM ===========
// Economics vs bf16 (r10, 112k cyc/block): MFMA instrs /4 (K=128/instr at
// 1.9x rate), LDS fragment bytes /2, staged bytes /2 -> every pipe shrinks.
// LDS (128 KB): buf*65536 + {A: row*128 + c*16} + {B: 32768 + row*128 + c*16}
//   rows 0..255 (fp8: 128 B per BK=128 row), chunks c 0..7.
// Swizzle (both-sides involution, rule #21): slot chunk c holds global chunk
// c ^ (row&7); staging source pre-swizzled cc=(t&7)^((t>>3)&7) (gload_lds
// writes linearly); read chunks (2fq+h)^(fr&7) -> 2 lanes per 16B column =
// free 2-way (m136).
// Loop (1 block/CU, 8 iters): reads(24 b128) -> MFMA m0-3 -> reads af4-7
// already issued -> lgkm0+BAR (all waves done reading buf cb) -> STAGE
// tile kt+2 into cb (write-after-read safe) -> MFMA m4-7 -> VM8 (proves
// tile kt+1; kt+2's 8 loads stay in flight, ~2 iters of lead) -> BAR.
// launch_bounds(512,2): VGPR cap 256; acc 128 + frags ~64 + misc fits.
// ((512,4) would cap 64 -> acc spill -> r4's 13.9GB disaster.)
// MFMA operand roles (r7-proven under swap): first arg = weights (v rows,
// instruction-A, fmt cbsz=0 fp8, scaleA=0x7B7B.. = 2^-4), second = h
// (blgp=0, scaleB=0x7F7F.. = 1.0). Uniform scale bytes => block-to-byte
// mapping irrelevant. C/D layout shape-determined (m127): col=lane&15 (m),
// row=fq*4+j (v) -> same float4-store epilogue as r7-r10 (WRITE 513MB ideal).
#define BAR __builtin_amdgcn_s_barrier()
#define LGKM0 asm volatile("s_waitcnt lgkmcnt(0)" ::: "memory")
#define VM8 asm volatile("s_waitcnt vmcnt(8)" ::: "memory")

__global__ __launch_bounds__(512, 2) void gemm_geo(
    const unsigned char* __restrict__ h8, const unsigned char* __restrict__ w8,
    const float* __restrict__ h0, const float* __restrict__ wtime,
    const float* __restrict__ ls, float* __restrict__ out) {
  __shared__ __align__(16) char smem[131072];

  const int t = threadIdx.x;
  const int wave = t >> 6, lane = t & 63;
  const int fr = lane & 15, fq = lane >> 4;
  const int wm = wave >> 2, wn = wave & 3;  // 2 (M) x 4 (N) wave grid

  // XCD-bijective grid: 2000 blocks (125 v-tiles x 16 m-tiles), 250/XCD;
  // 16 consecutive blocks share one B-panel (spatial L2 reuse, r5-proven).
  const int bid = blockIdx.x;
  const int swz = (bid & 7) * 250 + (bid >> 3);
  const int tile_v = swz >> 4;
  const int tile_m = swz & 15;
  const int row0 = tile_m * 256;
  const int col0 = tile_v * 256;

  // read-side lane constants (bytes)
  const int xorv = fr & 7;
  const int c0 = ((2 * fq) ^ xorv) * 16;
  const int c1 = ((2 * fq + 1) ^ xorv) * 16;
  const int a_base = (wm * 128 + fr) * 128;          // + cbo + im*2048
  const int b_base = 32768 + (wn * 64 + fr) * 128;   // + cbo + iv*2048

  auto RDF = [&](int off) -> int8v {
    int4v lo = *(const int4v*)(smem + off + c0);
    int4v hi = *(const int4v*)(smem + off + c1);
    return (int8v){lo[0], lo[1], lo[2], lo[3], hi[0], hi[1], hi[2], hi[3]};
  };

  // staging: thread t -> row t>>3 (+64/batch), slot chunk t&7; source chunk
  // pre-swizzled
  const int cc = (t & 7) ^ ((t >> 3) & 7);
  const unsigned char* pA = h8 + ((long)row0 + (t >> 3)) * K_TOT + cc * 16;
  const unsigned char* pB = w8 + ((long)col0 + (t >> 3)) * K_TOT + cc * 16;
  const int dst_w = wave * 1024;  // wave-uniform; HW adds lane*16

  auto STAGE = [&](int kt, int bufo) {
#pragma unroll
    for (int hh = 0; hh < 4; ++hh) {
      gload_lds16(pA + (long)hh * 65536 + kt * 128,
                  smem + bufo + hh * 8192 + dst_w);
      gload_lds16(pB + (long)hh * 65536 + kt * 128,
                  smem + bufo + 32768 + hh * 8192 + dst_w);
    }
  };

  f32x4 acc[8][4];
#pragma unroll
  for (int i = 0; i < 8; ++i)
#pragma unroll
    for (int j = 0; j < 4; ++j) acc[i][j] = (f32x4)(0.0f);

  // prologue: tiles 0,1 -> bufs 0,1 (8 loads each); VM8 proves tile0.
  STAGE(0, 0);
  STAGE(1, 65536);
  VM8;
  BAR;

#pragma unroll 1
  for (int kt = 0; kt < 8; ++kt) {
    const int cbo = (kt & 1) << 16;
    const int skt = (kt + 2 < 8) ? kt + 2 : 7;  // clamped redundant tail

    int8v bv[4], av[4];
#pragma unroll
    for (int iv = 0; iv < 4; ++iv) bv[iv] = RDF(cbo + b_base + iv * 2048);
#pragma unroll
    for (int im = 0; im < 4; ++im) av[im] = RDF(cbo + a_base + im * 2048);

    __builtin_amdgcn_s_setprio(1);
#pragma unroll
    for (int im = 0; im < 4; ++im)
#pragma unroll
      for (int iv = 0; iv < 4; ++iv)
        acc[im][iv] = __builtin_amdgcn_mfma_scale_f32_16x16x128_f8f6f4(
            bv[iv], av[im], acc[im][iv], 0, 0, 0, 0x7B7B7B7B, 0, 0x7F7F7F7F);
    __builtin_amdgcn_s_setprio(0);

    int8v av2[4];
#pragma unroll
    for (int im = 0; im < 4; ++im)
      av2[im] = RDF(cbo + a_base + (4 + im) * 2048);
    LGKM0;
    __builtin_amdgcn_sched_barrier(0);
    BAR;  // all waves done reading buf cbo -> safe to overwrite it

    STAGE(skt, cbo);  // tile kt+2 -> same-parity buffer (double buffer)

    __builtin_amdgcn_s_setprio(1);
#pragma unroll
    for (int im = 0; im < 4; ++im)
#pragma unroll
      for (int iv = 0; iv < 4; ++iv)
        acc[4 + im][iv] = __builtin_amdgcn_mfma_scale_f32_16x16x128_f8f6f4(
            bv[iv], av2[im], acc[4 + im][iv], 0, 0, 0, 0x7B7B7B7B, 0,
            0x7F7F7F7F);
    __builtin_amdgcn_s_setprio(0);

    // proves tile kt+1 landed (its 8 loads are >=8 back; kt+2's 8 in flight)
    VM8;
    BAR;
  }

  // fused epilogue (r7-proven): x = h0*w_time - dot; d2 = acosh(x)^2;
  // out = -tau*d2. v on acc-reg axis -> float4 stores.
  const float ntau = -fminf(fmaxf(ls[0], 0.01f), 2.5f);
  const float LN2 = 0.69314718055994531f;
  f32x4 wt4[4];
#pragma unroll
  for (int iv = 0; iv < 4; ++iv)
    wt4[iv] = *(const f32x4*)&wtime[col0 + wn * 64 + iv * 16 + fq * 4];
#pragma unroll
  for (int im = 0; im < 8; ++im) {
    const float hh = h0[row0 + wm * 128 + im * 16 + fr];
    float* orow =
        out + (long)(row0 + wm * 128 + im * 16 + fr) * V_TOT + col0 + wn * 64;
#pragma unroll
    for (int iv = 0; iv < 4; ++iv) {
      f32x4 r;
#pragma unroll
      for (int j = 0; j < 4; ++j) {
        float x = fmaf(hh, wt4[iv][j], -acc[im][iv][j]);
        float xm1 = fmaxf(x - 1.0f, 0.0f);
        float arg = fmaxf(fmaf(x, x, -1.0f), 0.0f);
        float lg2 = __builtin_amdgcn_logf(x + __builtin_amdgcn_sqrtf(arg));
        float dex = LN2 * lg2;
        float d2_exact = dex * dex;
        float ts = fmaf(xm1, -1.0f / 12.0f, 1.0f);
        float d2_tay = 2.0f * xm1 * ts * ts;
        float d2 = (xm1 < 1e-3f) ? d2_tay : d2_exact;
        r[j] = ntau * d2;
      }
      *(f32x4*)(orow + iv * 16 + fq * 4) = r;
    }
  }
}

extern "C" void kernel_launch(void* const* d_in, const int* in_sizes, int n_in,
                              void* d_out, int out_size, void* d_ws, size_t ws_size,
                              hipStream_t stream) {
  const float* h = (const float*)d_in[0];   // [2,2048,1025]
  const float* w = (const float*)d_in[1];   // [32000,1024]
  const float* ls = (const float*)d_in[2];  // scalar
  float* out = (float*)d_out;               // [2,2048,32000] fp32

  char* ws = (char*)d_ws;
  unsigned char* w8 = (unsigned char*)ws;                     // 32,768,000 B
  unsigned char* h8 = (unsigned char*)(ws + 32768000);        // 4,194,304 B
  float* wtime = (float*)(ws + 32768000 + 4194304);           // 128,000 B
  float* h0 = (float*)(ws + 32768000 + 4194304 + 128000);     // 16,384 B

  prep_h<<<M_TOT, 256, 0, stream>>>(h, h8, h0);
  prep_w<<<V_TOT, 256, 0, stream>>>(w, w8, wtime);
  gemm_geo<<<2000, 512, 0, stream>>>(h8, w8, h0, wtime, ls, out);
}